// Round 15
// baseline (195.928 us; speedup 1.0000x reference)
//
#include <hip/hip_runtime.h>
#include <hip/hip_bf16.h>
#include <math.h>

#define D_MODEL 1024
#define N_HEADS 16
#define D_K     64
#define S_LEN   2048
#define B_SZ    2

typedef unsigned short u16;
typedef unsigned int   u32;
using short8  = __attribute__((ext_vector_type(8))) short;
using ushort8 = __attribute__((ext_vector_type(8))) unsigned short;
using f32x4   = __attribute__((ext_vector_type(4))) float;

__device__ inline float bf2f(u16 u) { return __uint_as_float((u32)u << 16); }
__device__ inline u16 f2bf(float f) {
    __hip_bfloat16 h = __float2bfloat16(f);   // RNE
    return *(u16*)&h;
}
// raw v_exp_f32 (2^x).  __exp2f does not exist in HIP device code.
__device__ inline float fast_exp2(float x) { return __builtin_amdgcn_exp2f(x); }
__device__ inline void gload_lds16(const void* g, void* l) {
    __builtin_amdgcn_global_load_lds(
        (const __attribute__((address_space(1))) unsigned int*)g,
        (__attribute__((address_space(3))) unsigned int*)l, 16, 0, 0);
}

// ---------------------------------------------------------------------------
// fp32 -> bf16 cast for all three inputs in ONE launch (x | W_qkv | W_out).
// ---------------------------------------------------------------------------
__global__ __launch_bounds__(256)
void cast3_f32_bf16(const float* __restrict__ a, u16* __restrict__ ao, int na4,
                    const float* __restrict__ bsrc, u16* __restrict__ bo, int nb4,
                    const float* __restrict__ c, u16* __restrict__ co, int nc4) {
    int j = blockIdx.x * 256 + threadIdx.x;
    const float* src; u16* dst;
    if (j < na4) { src = a; dst = ao; }
    else {
        j -= na4;
        if (j < nb4) { src = bsrc; dst = bo; }
        else {
            j -= nb4;
            if (j >= nc4) return;
            src = c; dst = co;
        }
    }
    float4 v = ((const float4*)src)[j];
    ushort4 u;
    u.x = f2bf(v.x); u.y = f2bf(v.y); u.z = f2bf(v.z); u.w = f2bf(v.w);
    ((ushort4*)dst)[j] = u;
}

// ---------------------------------------------------------------------------
// One MFMA quadrant (compile-time mh/nh per rule #20: all acc indices const).
// ---------------------------------------------------------------------------
template<int MH, int NH>
__device__ __forceinline__ void mm_quad(const short8 (&af)[4][2],
                                        const short8 (&bf)[2][2],
                                        f32x4 (&acc)[8][4]) {
    __builtin_amdgcn_s_setprio(1);
#pragma unroll
    for (int kk = 0; kk < 2; kk++)
#pragma unroll
        for (int m = 0; m < 4; m++)
#pragma unroll
            for (int n = 0; n < 2; n++)
                acc[MH * 4 + m][NH * 2 + n] = __builtin_amdgcn_mfma_f32_16x16x32_bf16(
                    af[m][kk], bf[n][kk], acc[MH * 4 + m][NH * 2 + n], 0, 0, 0);
    __builtin_amdgcn_s_setprio(0);
}

// ---------------------------------------------------------------------------
// gemm1, 8-PHASE 256x256 schedule (T3+T4+T2+T5) with FUSED RoPE epilogue.
//
// R12 fix vs R11 (62.6 us, VALUBusy 10% -- waves parked on waitcnt):
//  * LDS split into FOUR distinct __shared__ arrays (Ab0/Ab1/Bb0/Bb1),
//    buffer chosen at COMPILE TIME per call site.  R11's single L[] made
//    the compiler's LDS-DMA alias tracking conservative: every ds-read
//    drained the whole outstanding global_load_lds queue (incl. the
//    same-phase prefetch) -> ~1 memory latency per phase (~1160 cy
//    measured).  Distinct objects -> precise per-DMA waits -> the manual
//    counted vmcnt(4) becomes the binding schedule (T4).
//  * Plain s_barrier (no sched_barrier(0) wrapping -- m141: order-pinning
//    regressed to 510 TF).
// Dataflow (staging schedule, vmcnt counts, swizzle, fragment addressing,
// RoPE epilogue) byte-identical to R11, which PASSED refcheck.
// Compiler-inserted precise waits still guard correctness wherever code
// motion puts the reads; the manual vmcnt only sets the schedule.
// ---------------------------------------------------------------------------
__global__ __launch_bounds__(512, 2)
void gemm_qkv_rope(const u16* __restrict__ A, const u16* __restrict__ B,
                   u16* __restrict__ Cout, const int* __restrict__ pos) {
    __shared__ u16 Ab0[16384];        // A buf0: [2 half][128 r][64 k]
    __shared__ u16 Ab1[16384];        // A buf1
    __shared__ u16 Bb0[16384];        // B buf0
    __shared__ u16 Bb1[16384];        // B buf1   (4 x 32 KB = 128 KB)

    const int tid  = threadIdx.x;
    const int lane = tid & 63;
    const int wv   = tid >> 6;        // 0..7
    const int wm2  = wv >> 2;         // 0..1  (M half)
    const int wn4  = wv & 3;          // 0..3  (N quarter)
    const int l15  = lane & 15;
    const int quad = lane >> 4;
    const int row0 = blockIdx.y * 256;
    const int col0 = blockIdx.x * 256;

    f32x4 acc[8][4] = {};
    short8 af[4][2], bf0[2][2], bf1[2][2];

    // stage one half-tile (128 rows x 64 k), K-tile kt, half h, into array Lb.
    // Global source chunk pre-swizzled: slot (r,c) <- global chunk c^(r&7).
    auto STAGEH = [&](const u16* gbase, int grow0, int kt, int h, u16* Lb) {
        const int ktw = (kt & 15) * 64;
#pragma unroll
        for (int i = 0; i < 2; i++) {
            int idx = i * 512 + tid;               // 0..1023
            int r   = idx >> 3;
            int c   = idx & 7;
            int cs  = c ^ (r & 7);
            gload_lds16(gbase + (size_t)(grow0 + h * 128 + r) * 1024 + ktw + cs * 8,
                        &Lb[h * 8192 + (i * 512 + wv * 64) * 8]);
        }
    };
    // fragment reads (swizzled chunk: (kk*4+quad)^(l15&7); row&7 == l15&7).
    auto LDA = [&](short8 (&dst)[4][2], const u16* Lb, int mh) {
#pragma unroll
        for (int m = 0; m < 4; m++)
#pragma unroll
            for (int kk = 0; kk < 2; kk++)
                dst[m][kk] = *(const short8*)&Lb[wm2 * 8192
                    + ((mh * 4 + m) * 16 + l15) * 64
                    + (((kk * 4 + quad) ^ (l15 & 7)) * 8)];
    };
    auto LDB = [&](short8 (&dst)[2][2], const u16* Lb, int nh) {
#pragma unroll
        for (int n = 0; n < 2; n++)
#pragma unroll
            for (int kk = 0; kk < 2; kk++)
                dst[n][kk] = *(const short8*)&Lb[(wn4 >> 1) * 8192
                    + ((wn4 & 1) * 64 + (nh * 2 + n) * 16 + l15) * 64
                    + (((kk * 4 + quad) ^ (l15 & 7)) * 8)];
    };

    // ---- prologue: B(0),A(0) -> buf0; B(1) -> buf1; retire tile 0 ----
    STAGEH(B, col0, 0, 0, Bb0);
    STAGEH(B, col0, 0, 1, Bb0);
    STAGEH(A, row0, 0, 0, Ab0);
    STAGEH(A, row0, 0, 1, Ab0);
    STAGEH(B, col0, 1, 0, Bb1);
    STAGEH(B, col0, 1, 1, Bb1);
    asm volatile("s_waitcnt vmcnt(4)" ::: "memory");
    __builtin_amdgcn_s_barrier();

    for (int it = 0; it < 8; it++) {
        const int t = 2 * it;
        // ph1
        LDA(af, Ab0, 0); LDB(bf0, Bb0, 0);
        STAGEH(A, row0, t + 1, 0, Ab1);
        __builtin_amdgcn_s_barrier();
        mm_quad<0, 0>(af, bf0, acc);
        __builtin_amdgcn_s_barrier();
        // ph2
        LDB(bf1, Bb0, 1);
        STAGEH(A, row0, t + 1, 1, Ab1);
        __builtin_amdgcn_s_barrier();
        mm_quad<0, 1>(af, bf1, acc);
        __builtin_amdgcn_s_barrier();
        // ph3
        LDA(af, Ab0, 1);
        STAGEH(B, col0, t + 2, 0, Bb0);
        __builtin_amdgcn_s_barrier();
        mm_quad<1, 0>(af, bf0, acc);
        __builtin_amdgcn_s_barrier();
        // ph4
        STAGEH(B, col0, t + 2, 1, Bb0);
        __builtin_amdgcn_s_barrier();
        mm_quad<1, 1>(af, bf1, acc);
        asm volatile("s_waitcnt vmcnt(4)" ::: "memory");
        __builtin_amdgcn_s_barrier();
        // ph5
        LDA(af, Ab1, 0); LDB(bf0, Bb1, 0);
        STAGEH(A, row0, t + 2, 0, Ab0);
        __builtin_amdgcn_s_barrier();
        mm_quad<0, 0>(af, bf0, acc);
        __builtin_amdgcn_s_barrier();
        // ph6
        LDB(bf1, Bb1, 1);
        STAGEH(A, row0, t + 2, 1, Ab0);
        __builtin_amdgcn_s_barrier();
        mm_quad<0, 1>(af, bf1, acc);
        __builtin_amdgcn_s_barrier();
        // ph7
        LDA(af, Ab1, 1);
        STAGEH(B, col0, t + 3, 0, Bb1);
        __builtin_amdgcn_s_barrier();
        mm_quad<1, 0>(af, bf0, acc);
        __builtin_amdgcn_s_barrier();
        // ph8
        STAGEH(B, col0, t + 3, 1, Bb1);
        __builtin_amdgcn_s_barrier();
        mm_quad<1, 1>(af, bf1, acc);
        asm volatile("s_waitcnt vmcnt(4)" ::: "memory");
        __builtin_amdgcn_s_barrier();
    }
    asm volatile("s_waitcnt vmcnt(0)" ::: "memory");

    // ---- epilogue: fused RoPE (verified R10 math; R11 geometry) ----
    const int cr = quad * 4;
    const int cc = l15;
    const int cb = col0 + wn4 * 64 + cc;      // lane's column base
    const int w  = cb >> 10;                  // 0=Q 1=K 2=V (block-uniform)
    const float CLOG = -0.41524101186092056f; // -log2(10000)/32
    const float qsc  = (w == 0) ? 0.18033688011112042f : 1.0f; // (1/8)*log2e
    float invf[4];
#pragma unroll
    for (int nj = 0; nj < 4; nj++)
        invf[nj] = fast_exp2((float)(((cb + nj * 16) & 63) >> 1) * CLOG);

#pragma unroll
    for (int mi = 0; mi < 8; mi++) {
#pragma unroll
        for (int r = 0; r < 4; r++) {
            int rr = row0 + wm2 * 128 + mi * 16 + cr + r;
            float p = (w == 2) ? 0.f : (float)pos[rr & (S_LEN - 1)];
#pragma unroll
            for (int nj = 0; nj < 4; nj++) {
                float v = acc[mi][nj][r];
                float partner = __shfl_xor(v, 1, 64);
                float res;
                if (w == 2) {
                    res = v;
                } else {
                    float sn, cs;
                    __sincosf(p * invf[nj], &sn, &cs);
                    res = ((cc & 1) ? (partner * sn + v * cs)
                                    : (v * cs - partner * sn)) * qsc;
                }
                Cout[(size_t)rr * (3 * D_MODEL) + cb + nj * 16] = f2bf(res);
            }
        }
    }
}

// ---------------------------------------------------------------------------
// 64x128-tile 2-phase GEMM for gemm2 (M=4096, N=1024 -> 512 blocks = 2/CU).
// f32 output.  (verified R8)
// ---------------------------------------------------------------------------
__global__ __launch_bounds__(256)
void gemm_bt_mfma_64r(const u16* __restrict__ A, const u16* __restrict__ B,
                      float* __restrict__ Cout, int M, int N, int K) {
    __shared__ u16 As[2][64 * 32];
    __shared__ u16 Bs[2][128 * 32];
    const int tid  = threadIdx.x;
    const int lane = tid & 63;
    const int wv   = tid >> 6;
    const int wm   = wv >> 1, wn = wv & 1;
    const int row0 = blockIdx.y * 64;
    const int col0 = blockIdx.x * 128;

    const int lr = lane >> 2;
    const int lc = (lane & 3) * 8;

    f32x4 acc[2][4] = {};

    auto STAGE = [&](int k0, int bf) {
        gload_lds16(A + (size_t)(row0 + wv * 16 + lr) * K + k0 + lc, &As[bf][(wv * 16) * 32]);
#pragma unroll
        for (int t = 0; t < 2; t++) {
            int rblk = wv * 32 + t * 16;
            gload_lds16(B + (size_t)(col0 + rblk + lr) * K + k0 + lc, &Bs[bf][rblk * 32]);
        }
    };

    STAGE(0, 0);
    __syncthreads();

    int cur = 0;
    for (int k0 = 0; k0 < K; k0 += 32) {
        if (k0 + 32 < K) STAGE(k0 + 32, cur ^ 1);

        short8 af[2], bfr[4];
#pragma unroll
        for (int mi = 0; mi < 2; mi++)
            af[mi] = *(const short8*)&As[cur][(wm * 32 + mi * 16 + (lane & 15)) * 32 + (lane >> 4) * 8];
#pragma unroll
        for (int nj = 0; nj < 4; nj++)
            bfr[nj] = *(const short8*)&Bs[cur][(wn * 64 + nj * 16 + (lane & 15)) * 32 + (lane >> 4) * 8];
#pragma unroll
        for (int mi = 0; mi < 2; mi++)
#pragma unroll
            for (int nj = 0; nj < 4; nj++)
                acc[mi][nj] = __builtin_amdgcn_mfma_f32_16x16x32_bf16(
                    af[mi], bfr[nj], acc[mi][nj], 0, 0, 0);

        __syncthreads();
        cur ^= 1;
    }

    const int cr = (lane >> 4) * 4;
    const int cc = lane & 15;
#pragma unroll
    for (int mi = 0; mi < 2; mi++) {
#pragma unroll
        for (int nj = 0; nj < 4; nj++) {
            int c = col0 + wn * 64 + nj * 16 + cc;
#pragma unroll
            for (int r = 0; r < 4; r++) {
                int rr = row0 + wm * 32 + mi * 16 + cr + r;
                Cout[(size_t)rr * N + c] = acc[mi][nj][r];
            }
        }
    }
}

// ---------------------------------------------------------------------------
// V transpose only.  qkv V slice (B,S,3,H,D) -> VT (B,H,D,S).  64x64 tile.
// ---------------------------------------------------------------------------
__global__ __launch_bounds__(256)
void vtrans(const u16* __restrict__ qkv, u16* __restrict__ VT) {
    __shared__ u16 t[64][68];
    const int bid = blockIdx.x;
    const int tid = threadIdx.x;
    const int st = bid & 31, h = (bid >> 5) & 15, b = bid >> 9;
    const int bh = b * N_HEADS + h;
#pragma unroll
    for (int i = 0; i < 4; i++) {
        int e  = tid + i * 256;
        int sl = e >> 4;
        int c4 = e & 15;
        ushort4 v = *(const ushort4*)&qkv[((size_t)(b * S_LEN + st * 64 + sl) * 3 + 2) * D_MODEL
                                          + h * D_K + c4 * 4];
        *(ushort4*)&t[sl][c4 * 4] = v;
    }
    __syncthreads();
#pragma unroll
    for (int i = 0; i < 4; i++) {
        int e  = tid + i * 256;
        int d  = e >> 4;
        int s4 = e & 15;
        ushort4 o;
        o.x = t[s4 * 4 + 0][d];
        o.y = t[s4 * 4 + 1][d];
        o.z = t[s4 * 4 + 2][d];
        o.w = t[s4 * 4 + 3][d];
        *(ushort4*)&VT[((size_t)bh * D_K + d) * S_LEN + st * 64 + s4 * 4] = o;
    }
}

// ---------------------------------------------------------------------------
// One attention step (scores in log2 domain; softmax via fast_exp2).
// S^T = K*Q^T; online softmax per lane (one query); O^T = V^T*P^T in regs;
// T13 defer-max THR=12; tree reductions.  (verified R10)
// ---------------------------------------------------------------------------
__device__ __forceinline__ void attn_step(
    const u16* __restrict__ Ksc, const u16* __restrict__ Vsc,
    u16* __restrict__ Psw,
    short8 (&qf)[2], f32x4 (&acc)[4], float& mq, float& lq,
    int k0, int qw0, bool diag, int l15, int quad, int qsw)
{
    f32x4 s[4] = {};
    __builtin_amdgcn_s_setprio(1);
#pragma unroll
    for (int kf = 0; kf < 2; kf++)
#pragma unroll
        for (int nj = 0; nj < 4; nj++) {
            short8 kfr = *(const short8*)&Ksc[kf * 2048 + (nj * 16 + l15) * 32 + qsw * 8];
            s[nj] = __builtin_amdgcn_mfma_f32_16x16x32_bf16(kfr, qf[kf], s[nj], 0, 0, 0);
        }
    __builtin_amdgcn_s_setprio(0);

    if (diag) {
        const int row_g = qw0 + l15;
#pragma unroll
        for (int nj = 0; nj < 4; nj++)
#pragma unroll
            for (int r = 0; r < 4; r++) {
                int key_g = k0 + nj * 16 + quad * 4 + r;
                if (key_g > row_g) s[nj][r] = -INFINITY;
            }
    }

    float mx[4];
#pragma unroll
    for (int nj = 0; nj < 4; nj++)
        mx[nj] = fmaxf(fmaxf(s[nj][0], s[nj][1]), fmaxf(s[nj][2], s[nj][3]));
    float rmax = fmaxf(fmaxf(mx[0], mx[1]), fmaxf(mx[2], mx[3]));
    rmax = fmaxf(rmax, __shfl_xor(rmax, 16, 64));
    rmax = fmaxf(rmax, __shfl_xor(rmax, 32, 64));

    if (!__all(rmax <= mq + 12.f)) {
        float mn = fmaxf(mq, rmax);
        float alpha = fast_exp2(mq - mn);
        mq = mn;
        lq *= alpha;
#pragma unroll
        for (int nj = 0; nj < 4; nj++)
#pragma unroll
            for (int r = 0; r < 4; r++) acc[nj][r] *= alpha;
    }

    float rs[4];
#pragma unroll
    for (int nj = 0; nj < 4; nj++) {
        float p0 = fast_exp2(s[nj][0] - mq);
        float p1 = fast_exp2(s[nj][1] - mq);
        float p2 = fast_exp2(s[nj][2] - mq);
        float p3 = fast_exp2(s[nj][3] - mq);
        s[nj][0] = p0; s[nj][1] = p1; s[nj][2] = p2; s[nj][3] = p3;
        rs[nj] = (p0 + p1) + (p2 + p3);
    }
    float rsum = (rs[0] + rs[1]) + (rs[2] + rs[3]);
    rsum += __shfl_xor(rsum, 16, 64);
    rsum += __shfl_xor(rsum, 32, 64);
    lq += rsum;

#pragma unroll
    for (int nj = 0; nj < 4; nj++) {
        u32 lo = ((u32)f2bf(s[nj][1]) << 16) | f2bf(s[nj][0]);
        u32 hi = ((u32)f2bf(s[nj][3]) << 16) | f2bf(s[nj][2]);
        uint2 pk; pk.x = lo; pk.y = hi;
        *(uint2*)&Psw[l15 * 68 + nj * 16 + quad * 4] = pk;
    }

    __builtin_amdgcn_s_setprio(1);
#pragma unroll
    for (int kf = 0; kf < 2; kf++) {
        const u16* pp = &Psw[l15 * 68 + kf * 32 + quad * 8];
        uint2 plo = *(const uint2*)pp;
        uint2 phi = *(const uint2*)(pp + 4);
        u32 praw[4] = { plo.x, plo.y, phi.x, phi.y };
        short8 pf = *(const short8*)praw;
#pragma unroll
        for (int nj = 0; nj < 4; nj++) {
            short8 vf = *(const short8*)&Vsc[kf * 2048 + (nj * 16 + l15) * 32 + qsw * 8];
            acc[nj] = __builtin_amdgcn_mfma_f32_16x16x32_bf16(vf, pf, acc[nj], 0, 0, 0);
        }
    }
    __builtin_amdgcn_s_setprio(0);
}

// ---------------------------------------------------------------------------
// MFMA flash attention v8 (causal): KEY-SPLIT pairs + T2 swizzle + T14.
// (verified R10)
// ---------------------------------------------------------------------------
__global__ __launch_bounds__(256)
void attn_mfma(const u16* __restrict__ qkv, const u16* __restrict__ VT,
               u16* __restrict__ out, float* __restrict__ partO,
               float* __restrict__ partML) {
    __shared__ u16 Ks[2][64 * 32];
    __shared__ u16 VsT[2][64 * 32];
    __shared__ u16 Ps[4][16 * 68];

    const int tid  = threadIdx.x;
    const int lane = tid & 63;
    const int wv   = tid >> 6;

    const int bid  = blockIdx.x;
    const int idx  = bid >> 3;
    const int bh   = (bid & 7) * 4 + (idx >> 5);
    const int rem  = idx & 31;
    const int pr   = rem >> 1;
    const int role = rem & 1;
    const int qtH  = 31 - pr;
    const int qtL  = pr;
    const int h    = bh & (N_HEADS - 1);
    const int b    = bh >> 4;

    const int l15  = lane & 15;
    const int quad = lane >> 4;
    const int qsw  = quad ^ ((l15 >> 1) & 3);
    const int qw0H = qtH * 64 + wv * 16;

    const size_t vtb = (size_t)bh * D_K * S_LEN;
    u16* Psw = &Ps[wv][0];
    const int lr  = lane >> 2;
    const int csw = ((lane & 3) ^ ((lane >> 3) & 3)) * 8;

    auto STAGE = [&](int kts) {
        const int k0s = kts * 64;
#pragma unroll
        for (int kf = 0; kf < 2; kf++)
            gload_lds16(qkv + ((size_t)(b * S_LEN + k0s + wv * 16 + lr) * 3 + 1) * D_MODEL
                            + h * D_K + kf * 32 + csw,
                        &Ks[kf][(wv * 16) * 32]);
#pragma unroll
        for (int kc = 0; kc < 2; kc++)
            gload_lds16(VT + vtb + (size_t)(wv * 16 + lr) * S_LEN + k0s + kc * 32 + csw,
                        &VsT[kc][(wv * 16) * 32]);
    };

    ushort8 kreg[2], vreg[2];
    auto REGLOAD = [&](int kts) {
        const int k0s = kts * 64;
#pragma unroll
        for (int kf = 0; kf < 2; kf++)
            kreg[kf] = *(const ushort8*)&qkv[((size_t)(b * S_LEN + k0s + wv * 16 + lr) * 3 + 1) * D_MODEL
                                             + h * D_K + kf * 32 + csw];
#pragma unroll
        for (int kc = 0; kc < 2; kc++)
            vreg[kc] = *(const ushort8*)&VT[vtb + (size_t)(wv * 16 + lr) * S_LEN + k0s + kc * 32 + csw];
    };
    auto LDSW = [&]() {
#pragma unroll
        for (int kf = 0; kf < 2; kf++)
            *(ushort8*)&Ks[kf][(wv * 16) * 32 + lane * 8] = kreg[kf];
#pragma unroll
        for (int kc = 0; kc < 2; kc++)
            *(ushort8*)&VsT[kc][(wv * 16) * 32 + lane * 8] = vreg[kc];
    };

    short8 qfH[2];
#pragma unroll
    for (int kf = 0; kf < 2; kf++)
        qfH[kf] = *(const short8*)&qkv[((size_t)(b * S_LEN + qw0H + l15) * 3 + 0) * D_MODEL
                                       + h * D_K + kf * 32 + quad * 8];
    f32x4 accH[4] = {};
    float mqH = -INFINITY, lqH = 0.f;

    const int kbeg = role ? 17 : 0;
    const int kend = role ? qtH : 16;
    if (kbeg <= kend) {
        STAGE(kbeg);
        __syncthreads();
        for (int kt = kbeg; kt <= kend; kt++) {
            const bool more = kt < kend;
            if (more) REGLOAD(kt + 1);
            attn_step(&Ks[0][0], &VsT[0][0], Psw, qfH, accH, mqH, lqH,
                      kt * 64, qw0H, kt == qtH, l15, quad, qsw);
            __syncthreads();
            if (more) { LDSW(); __syncthreads(); }
        }
    }

    {
        const size_t unit = (size_t)(bh * 16 + (qtH - 16)) * 2 + role;
        float* Od = partO + unit * 4096 + (size_t)(wv * 16 + l15) * 64;
#pragma unroll
        for (int nj = 0; nj < 4; nj++)
            *(f32x4*)&Od[nj * 16 + quad * 4] = accH[nj];
        if (quad == 0) {
            float* ML = partML + unit * 128;
            ML[wv * 16 + l15]      = mqH;
            ML[64 + wv * 16 + l15] = lqH;
        }
    }

    if (!role) return;

    const int qw0L = qtL * 64 + wv * 16;
    short8 qfL[2];
#pragma unroll
    for (int kf = 0; kf < 2; kf++)
        qfL[kf] = *(const short8*)&qkv[((size_t)(b * S_LEN + qw0L + l15) * 3 + 0) * D_MODEL
                                       + h * D_K + kf * 32 + quad * 8];
    f32x4 accL[4] = {};
    float mqL = -INFINITY, lqL = 0.f;

    STAGE(0);
    __syncthreads();
    for (int kt = 0; kt <= qtL; kt++) {
        const bool more = kt < qtL;
        if (more) REGLOAD(kt + 1);
        attn_step(&Ks[0][0], &VsT[0][0], Psw, qfL, accL, mqL, lqL,
                  kt * 64, qw0L, kt == qtL, l15, quad, qsw);
        __syncthreads();
        if (more) { LDSW(); __syncthreads(); }
    }

    float invl = 1.f / lqL;
#pragma unroll
    for (int nj = 0; nj < 4; nj++) {
        ushort4 o;
        o.x = f2bf(accL[nj][0] * invl); o.y = f2bf(accL[nj][1] * invl);
        o.z = f2bf(accL[nj][2] * invl); o.w = f2bf(accL[nj][3] * invl);
        *(ushort4*)&out[(size_t)(b * S_LEN + qw0L + l15) * D_MODEL
                        + h * D_K + nj * 16 + quad * 4] = o;
    }
}

// ---------------------------------------------------------------------------
// Merge the two key-range partials of each H q-tile (log2 domain).
// ---------------------------------------------------------------------------
__global__ __launch_bounds__(256)
void attn_combine(const float* __restrict__ partO, const float* __restrict__ partML,
                  u16* __restrict__ out) {
    const int t16 = blockIdx.x & 15;
    const int bh  = blockIdx.x >> 4;
    const int h = bh & (N_HEADS - 1), b = bh >> 4;
    const int q0 = (t16 + 16) * 64;
    const int tid = threadIdx.x;
    const int q  = tid >> 2;
    const int d0 = (tid & 3) * 16;

    const size_t u0 = (size_t)(bh * 16 + t16) * 2;
    const float* O0 = partO + u0 * 4096;
    const float* O1 = O0 + 4096;
    const float* ML0 = partML + u0 * 128;
    const float* ML1 = ML0 + 128;

    float m0 = ML0[q], l0 = ML0[64 + q];
    float m1 = ML1[q], l1 = ML1[64 + q];
    float ms = fmaxf(m0, m1);
    float f0 = fast_exp2(m0 - ms), f1 = fast_exp2(m1 - ms);
    float inv = 1.f / (l0 * f0 + l1 * f1);
    f0 *= inv; f1 *= inv;
#pragma unroll
    for (int i = 0; i < 4; i++) {
        float4 a = *(const float4*)&O0[q * 64 + d0 + i * 4];
        float4 c = *(const float4*)&O1[q * 64 + d0 + i * 4];
        ushort4 o;
        o.x = f2bf(a.x * f0 + c.x * f1);
        o.y = f2bf(a.y * f0 + c.y * f1);
        o.z = f2bf(a.z * f0 + c.z * f1);
        o.w = f2bf(a.w * f0 + c.w * f1);
        *(ushort4*)&out[(size_t)(b * S_LEN + q0 + q) * D_MODEL + h * D_K + d0 + i * 4] = o;
    }
}

// ---------------------------------------------------------------------------
extern "C" void kernel_launch(void* const* d_in, const int* in_sizes, int n_in,
                              void* d_out, int out_size, void* d_ws, size_t ws_size,
                              hipStream_t stream) {
    const float* x    = (const float*)d_in[0];
    const int*   pos  = (const int*)d_in[1];
    const float* Wqkv = (const float*)d_in[2];
    const float* Wout = (const float*)d_in[3];
    float*       out  = (float*)d_out;

    const int M = B_SZ * S_LEN;   // 4096

    u16* qkvb = (u16*)d_ws;                            // 4096 x 3072
    u16* aob  = qkvb + (size_t)M * 3 * D_MODEL;        // 4096 x 1024
    u16* xb   = aob  + (size_t)M * D_MODEL;            // 4096 x 1024
    u16* wqb  = xb   + (size_t)M * D_MODEL;            // 3072 x 1024
    u16* wob  = wqb  + (size_t)3 * D_MODEL * D_MODEL;  // 1024 x 1024
    u16* vtb  = wob  + (size_t)D_MODEL * D_MODEL;      // 4096 x 1024
    float* partO  = (float*)(vtb + (size_t)M * D_MODEL);   // 1024 x 4096 f32
    float* partML = partO + (size_t)1024 * 4096;            // 1024 x 128 f32

    const int na4 = M * D_MODEL / 4;
    const int nb4 = 3 * D_MODEL * D_MODEL / 4;
    const int nc4 = D_MODEL * D_MODEL / 4;
    cast3_f32_bf16<<<(na4 + nb4 + nc4 + 255) / 256, 256, 0, stream>>>(
        x, xb, na4, Wqkv, wqb, nb4, Wout, wob, nc4);

    // gemm1: 8-phase 256^2 schedule + fused RoPE/Q-scale epilogue
    gemm_qkv_rope<<<dim3(3 * D_MODEL / 256, M / 256), 512, 0, stream>>>(
        xb, wqb, qkvb, pos);

    vtrans<<<1024, 256, 0, stream>>>(qkvb, vtb);

    attn_mfma<<<1024, 256, 0, stream>>>(qkvb, vtb, aob, partO, partML);
    attn_combine<<<512, 256, 0, stream>>>(partO, partML, aob);

    gemm_bt_mfma_64r<<<dim3(D_MODEL / 128, M / 64), 256, 0, stream>>>(
        aob, wob, out, M, D_MODEL, D_MODEL);
}

// Round 17
// 184.680 us; speedup vs baseline: 1.0609x; 1.0609x over previous
//
#include <hip/hip_runtime.h>
#include <hip/hip_bf16.h>
#include <math.h>

#define D_MODEL 1024
#define N_HEADS 16
#define D_K     64
#define S_LEN   2048
#define B_SZ    2

typedef unsigned short u16;
typedef unsigned int   u32;
using short8  = __attribute__((ext_vector_type(8))) short;
using ushort8 = __attribute__((ext_vector_type(8))) unsigned short;
using f32x4   = __attribute__((ext_vector_type(4))) float;

__device__ inline float bf2f(u16 u) { return __uint_as_float((u32)u << 16); }
__device__ inline u16 f2bf(float f) {
    __hip_bfloat16 h = __float2bfloat16(f);   // RNE
    return *(u16*)&h;
}
// raw v_exp_f32 (2^x).  __exp2f does not exist in HIP device code.
__device__ inline float fast_exp2(float x) { return __builtin_amdgcn_exp2f(x); }
__device__ inline void gload_lds16(const void* g, void* l) {
    __builtin_amdgcn_global_load_lds(
        (const __attribute__((address_space(1))) unsigned int*)g,
        (__attribute__((address_space(3))) unsigned int*)l, 16, 0, 0);
}

// ---------------------------------------------------------------------------
// fp32 -> bf16 cast for all three inputs in ONE launch (x | W_qkv | W_out).
// ---------------------------------------------------------------------------
__global__ __launch_bounds__(256)
void cast3_f32_bf16(const float* __restrict__ a, u16* __restrict__ ao, int na4,
                    const float* __restrict__ bsrc, u16* __restrict__ bo, int nb4,
                    const float* __restrict__ c, u16* __restrict__ co, int nc4) {
    int j = blockIdx.x * 256 + threadIdx.x;
    const float* src; u16* dst;
    if (j < na4) { src = a; dst = ao; }
    else {
        j -= na4;
        if (j < nb4) { src = bsrc; dst = bo; }
        else {
            j -= nb4;
            if (j >= nc4) return;
            src = c; dst = co;
        }
    }
    float4 v = ((const float4*)src)[j];
    ushort4 u;
    u.x = f2bf(v.x); u.y = f2bf(v.y); u.z = f2bf(v.z); u.w = f2bf(v.w);
    ((ushort4*)dst)[j] = u;
}

// ---------------------------------------------------------------------------
// gemm1 with FUSED RoPE epilogue (VERIFIED R10, 183.3-us state): 128x128
// tile, 2-phase double-buffer.  R15 post-mortem: the 8-phase 256^2 port
// peaked at 48.4 us (MfmaUtil 20%) -- structurally worse at this shape
// (192 blocks = 75% CU coverage, 1 block/CU lockstep) than this simple
// 2-phase at ~40 us with 3 blocks/CU.  Reverted per pre-commitment.
// Rotation: pair (2j,2j+1) lives in adjacent lanes -> one __shfl_xor.
// Q scaled by (1/8)*log2(e) so scores land in the log2 domain.
// ---------------------------------------------------------------------------
__global__ __launch_bounds__(256)
void gemm_qkv_rope(const u16* __restrict__ A, const u16* __restrict__ B,
                   u16* __restrict__ Cout, const int* __restrict__ pos,
                   int M, int N, int K) {
    __shared__ u16 As[2][128 * 32];
    __shared__ u16 Bs[2][128 * 32];
    const int tid  = threadIdx.x;
    const int lane = tid & 63;
    const int wv   = tid >> 6;
    const int wm   = wv >> 1, wn = wv & 1;
    const int row0 = blockIdx.y * 128;
    const int col0 = blockIdx.x * 128;

    const int lr = lane >> 2;
    const int lc = (lane & 3) * 8;

    f32x4 acc[4][4] = {};

    auto STAGE = [&](int k0, int bf) {
#pragma unroll
        for (int t = 0; t < 2; t++) {
            int rblk = wv * 32 + t * 16;
            gload_lds16(A + (size_t)(row0 + rblk + lr) * K + k0 + lc, &As[bf][rblk * 32]);
            gload_lds16(B + (size_t)(col0 + rblk + lr) * K + k0 + lc, &Bs[bf][rblk * 32]);
        }
    };

    STAGE(0, 0);
    __syncthreads();

    int cur = 0;
    for (int k0 = 0; k0 < K; k0 += 32) {
        if (k0 + 32 < K) STAGE(k0 + 32, cur ^ 1);

        short8 af[4], bfr[4];
#pragma unroll
        for (int mi = 0; mi < 4; mi++)
            af[mi] = *(const short8*)&As[cur][(wm * 64 + mi * 16 + (lane & 15)) * 32 + (lane >> 4) * 8];
#pragma unroll
        for (int nj = 0; nj < 4; nj++)
            bfr[nj] = *(const short8*)&Bs[cur][(wn * 64 + nj * 16 + (lane & 15)) * 32 + (lane >> 4) * 8];
#pragma unroll
        for (int mi = 0; mi < 4; mi++)
#pragma unroll
            for (int nj = 0; nj < 4; nj++)
                acc[mi][nj] = __builtin_amdgcn_mfma_f32_16x16x32_bf16(
                    af[mi], bfr[nj], acc[mi][nj], 0, 0, 0);

        __syncthreads();
        cur ^= 1;
    }

    // ---- epilogue: fused RoPE ----
    const int cr = (lane >> 4) * 4;
    const int cc = lane & 15;
    const int cb = col0 + wn * 64 + cc;       // this lane's column base
    const int w  = cb >> 10;                  // 0=Q 1=K 2=V (block-uniform)
    const float CLOG = -0.41524101186092056f; // -log2(10000)/32
    const float qsc  = (w == 0) ? 0.18033688011112042f : 1.0f; // (1/8)*log2e
    float invf[4];
#pragma unroll
    for (int nj = 0; nj < 4; nj++)
        invf[nj] = fast_exp2((float)(((cb + nj * 16) & 63) >> 1) * CLOG);

#pragma unroll
    for (int mi = 0; mi < 4; mi++) {
#pragma unroll
        for (int r = 0; r < 4; r++) {
            int rr = row0 + wm * 64 + mi * 16 + cr + r;
            float p = (w == 2) ? 0.f : (float)pos[rr & (S_LEN - 1)];
#pragma unroll
            for (int nj = 0; nj < 4; nj++) {
                float v = acc[mi][nj][r];
                float partner = __shfl_xor(v, 1, 64);
                float res;
                if (w == 2) {
                    res = v;
                } else {
                    float sn, cs;
                    __sincosf(p * invf[nj], &sn, &cs);
                    // even col: x1=v, x2=partner ; odd col: x1=partner, x2=v
                    res = ((cc & 1) ? (partner * sn + v * cs)
                                    : (v * cs - partner * sn)) * qsc;
                }
                Cout[(size_t)rr * N + cb + nj * 16] = f2bf(res);
            }
        }
    }
}

// ---------------------------------------------------------------------------
// 64x128-tile 2-phase GEMM for gemm2 (M=4096, N=1024 -> 512 blocks = 2/CU).
// f32 output.  (verified R8)
// ---------------------------------------------------------------------------
__global__ __launch_bounds__(256)
void gemm_bt_mfma_64r(const u16* __restrict__ A, const u16* __restrict__ B,
                      float* __restrict__ Cout, int M, int N, int K) {
    __shared__ u16 As[2][64 * 32];
    __shared__ u16 Bs[2][128 * 32];
    const int tid  = threadIdx.x;
    const int lane = tid & 63;
    const int wv   = tid >> 6;
    const int wm   = wv >> 1, wn = wv & 1;
    const int row0 = blockIdx.y * 64;
    const int col0 = blockIdx.x * 128;

    const int lr = lane >> 2;
    const int lc = (lane & 3) * 8;

    f32x4 acc[2][4] = {};

    auto STAGE = [&](int k0, int bf) {
        gload_lds16(A + (size_t)(row0 + wv * 16 + lr) * K + k0 + lc, &As[bf][(wv * 16) * 32]);
#pragma unroll
        for (int t = 0; t < 2; t++) {
            int rblk = wv * 32 + t * 16;
            gload_lds16(B + (size_t)(col0 + rblk + lr) * K + k0 + lc, &Bs[bf][rblk * 32]);
        }
    };

    STAGE(0, 0);
    __syncthreads();

    int cur = 0;
    for (int k0 = 0; k0 < K; k0 += 32) {
        if (k0 + 32 < K) STAGE(k0 + 32, cur ^ 1);

        short8 af[2], bfr[4];
#pragma unroll
        for (int mi = 0; mi < 2; mi++)
            af[mi] = *(const short8*)&As[cur][(wm * 32 + mi * 16 + (lane & 15)) * 32 + (lane >> 4) * 8];
#pragma unroll
        for (int nj = 0; nj < 4; nj++)
            bfr[nj] = *(const short8*)&Bs[cur][(wn * 64 + nj * 16 + (lane & 15)) * 32 + (lane >> 4) * 8];
#pragma unroll
        for (int mi = 0; mi < 2; mi++)
#pragma unroll
            for (int nj = 0; nj < 4; nj++)
                acc[mi][nj] = __builtin_amdgcn_mfma_f32_16x16x32_bf16(
                    af[mi], bfr[nj], acc[mi][nj], 0, 0, 0);

        __syncthreads();
        cur ^= 1;
    }

    const int cr = (lane >> 4) * 4;
    const int cc = lane & 15;
#pragma unroll
    for (int mi = 0; mi < 2; mi++) {
#pragma unroll
        for (int nj = 0; nj < 4; nj++) {
            int c = col0 + wn * 64 + nj * 16 + cc;
#pragma unroll
            for (int r = 0; r < 4; r++) {
                int rr = row0 + wm * 32 + mi * 16 + cr + r;
                Cout[(size_t)rr * N + c] = acc[mi][nj][r];
            }
        }
    }
}

// ---------------------------------------------------------------------------
// V transpose only.  qkv V slice (B,S,3,H,D) -> VT (B,H,D,S).  64x64 tile.
// ---------------------------------------------------------------------------
__global__ __launch_bounds__(256)
void vtrans(const u16* __restrict__ qkv, u16* __restrict__ VT) {
    __shared__ u16 t[64][68];
    const int bid = blockIdx.x;
    const int tid = threadIdx.x;
    const int st = bid & 31, h = (bid >> 5) & 15, b = bid >> 9;
    const int bh = b * N_HEADS + h;
#pragma unroll
    for (int i = 0; i < 4; i++) {
        int e  = tid + i * 256;
        int sl = e >> 4;
        int c4 = e & 15;
        ushort4 v = *(const ushort4*)&qkv[((size_t)(b * S_LEN + st * 64 + sl) * 3 + 2) * D_MODEL
                                          + h * D_K + c4 * 4];
        *(ushort4*)&t[sl][c4 * 4] = v;
    }
    __syncthreads();
#pragma unroll
    for (int i = 0; i < 4; i++) {
        int e  = tid + i * 256;
        int d  = e >> 4;
        int s4 = e & 15;
        ushort4 o;
        o.x = t[s4 * 4 + 0][d];
        o.y = t[s4 * 4 + 1][d];
        o.z = t[s4 * 4 + 2][d];
        o.w = t[s4 * 4 + 3][d];
        *(ushort4*)&VT[((size_t)bh * D_K + d) * S_LEN + st * 64 + s4 * 4] = o;
    }
}

// ---------------------------------------------------------------------------
// One attention step (scores in log2 domain; softmax via fast_exp2).
// S^T = K*Q^T; online softmax per lane (one query); O^T = V^T*P^T in regs;
// T13 defer-max THR=12.  SERIAL reductions restored: the R9/R10 tree
// rewrite measured +3 us (42.6 -> 45.6, only attn change, FETCH equal) --
// reverted to the 42.6-us form.
// ---------------------------------------------------------------------------
__device__ __forceinline__ void attn_step(
    const u16* __restrict__ Ksc, const u16* __restrict__ Vsc,
    u16* __restrict__ Psw,
    short8 (&qf)[2], f32x4 (&acc)[4], float& mq, float& lq,
    int k0, int qw0, bool diag, int l15, int quad, int qsw)
{
    // ---- S^T = K*Q^T : s[nj] rows=keys nj*16+quad*4+r, col=query l15 ----
    f32x4 s[4] = {};
    __builtin_amdgcn_s_setprio(1);
#pragma unroll
    for (int kf = 0; kf < 2; kf++)
#pragma unroll
        for (int nj = 0; nj < 4; nj++) {
            short8 kfr = *(const short8*)&Ksc[kf * 2048 + (nj * 16 + l15) * 32 + qsw * 8];
            s[nj] = __builtin_amdgcn_mfma_f32_16x16x32_bf16(kfr, qf[kf], s[nj], 0, 0, 0);
        }
    __builtin_amdgcn_s_setprio(0);

    // ---- causal mask (diagonal tile only) ----
    if (diag) {
        const int row_g = qw0 + l15;
#pragma unroll
        for (int nj = 0; nj < 4; nj++)
#pragma unroll
            for (int r = 0; r < 4; r++) {
                int key_g = k0 + nj * 16 + quad * 4 + r;
                if (key_g > row_g) s[nj][r] = -INFINITY;
            }
    }

    // ---- online softmax: one query per lane, 16 keys in-lane ----
    float rmax = s[0][0];
#pragma unroll
    for (int nj = 0; nj < 4; nj++)
#pragma unroll
        for (int r = 0; r < 4; r++) rmax = fmaxf(rmax, s[nj][r]);
    rmax = fmaxf(rmax, __shfl_xor(rmax, 16, 64));
    rmax = fmaxf(rmax, __shfl_xor(rmax, 32, 64));

    // T13 defer-max: only touch mq / rescale O when the max actually grew.
    if (!__all(rmax <= mq + 12.f)) {
        float mn = fmaxf(mq, rmax);
        float alpha = fast_exp2(mq - mn);
        mq = mn;
        lq *= alpha;
#pragma unroll
        for (int nj = 0; nj < 4; nj++)
#pragma unroll
            for (int r = 0; r < 4; r++) acc[nj][r] *= alpha;
    }

    float rsum = 0.f;
#pragma unroll
    for (int nj = 0; nj < 4; nj++)
#pragma unroll
        for (int r = 0; r < 4; r++) {
            float p = fast_exp2(s[nj][r] - mq);
            s[nj][r] = p;
            rsum += p;
        }
    rsum += __shfl_xor(rsum, 16, 64);
    rsum += __shfl_xor(rsum, 32, 64);
    lq += rsum;

    // ---- P (bf16 pairs) -> wave-private LDS strip [query][key] ----
#pragma unroll
    for (int nj = 0; nj < 4; nj++) {
        u32 lo = ((u32)f2bf(s[nj][1]) << 16) | f2bf(s[nj][0]);
        u32 hi = ((u32)f2bf(s[nj][3]) << 16) | f2bf(s[nj][2]);
        uint2 pk; pk.x = lo; pk.y = hi;
        *(uint2*)&Psw[l15 * 68 + nj * 16 + quad * 4] = pk;
    }
    // same-wave LDS RAW -> compiler inserts lgkmcnt wait

    // ---- O^T += V^T*P^T : acc[nj] rows = d = nj*16+quad*4+r, col = q = l15 --
    __builtin_amdgcn_s_setprio(1);
#pragma unroll
    for (int kf = 0; kf < 2; kf++) {
        const u16* pp = &Psw[l15 * 68 + kf * 32 + quad * 8];
        uint2 plo = *(const uint2*)pp;
        uint2 phi = *(const uint2*)(pp + 4);
        u32 praw[4] = { plo.x, plo.y, phi.x, phi.y };
        short8 pf = *(const short8*)praw;
#pragma unroll
        for (int nj = 0; nj < 4; nj++) {
            short8 vf = *(const short8*)&Vsc[kf * 2048 + (nj * 16 + l15) * 32 + qsw * 8];
            acc[nj] = __builtin_amdgcn_mfma_f32_16x16x32_bf16(vf, pf, acc[nj], 0, 0, 0);
        }
    }
    __builtin_amdgcn_s_setprio(0);
}

// ---------------------------------------------------------------------------
// MFMA flash attention v8 (causal): KEY-SPLIT pairs + T2 swizzle + T14.
// (verified R8/R10)
// ---------------------------------------------------------------------------
__global__ __launch_bounds__(256)
void attn_mfma(const u16* __restrict__ qkv, const u16* __restrict__ VT,
               u16* __restrict__ out, float* __restrict__ partO,
               float* __restrict__ partML) {
    __shared__ u16 Ks[2][64 * 32];
    __shared__ u16 VsT[2][64 * 32];
    __shared__ u16 Ps[4][16 * 68];

    const int tid  = threadIdx.x;
    const int lane = tid & 63;
    const int wv   = tid >> 6;

    const int bid  = blockIdx.x;
    const int idx  = bid >> 3;
    const int bh   = (bid & 7) * 4 + (idx >> 5);
    const int rem  = idx & 31;
    const int pr   = rem >> 1;
    const int role = rem & 1;
    const int qtH  = 31 - pr;
    const int qtL  = pr;
    const int h    = bh & (N_HEADS - 1);
    const int b    = bh >> 4;

    const int l15  = lane & 15;
    const int quad = lane >> 4;
    const int qsw  = quad ^ ((l15 >> 1) & 3);
    const int qw0H = qtH * 64 + wv * 16;

    const size_t vtb = (size_t)bh * D_K * S_LEN;
    u16* Psw = &Ps[wv][0];
    const int lr  = lane >> 2;
    const int csw = ((lane & 3) ^ ((lane >> 3) & 3)) * 8;

    auto STAGE = [&](int kts) {
        const int k0s = kts * 64;
#pragma unroll
        for (int kf = 0; kf < 2; kf++)
            gload_lds16(qkv + ((size_t)(b * S_LEN + k0s + wv * 16 + lr) * 3 + 1) * D_MODEL
                            + h * D_K + kf * 32 + csw,
                        &Ks[kf][(wv * 16) * 32]);
#pragma unroll
        for (int kc = 0; kc < 2; kc++)
            gload_lds16(VT + vtb + (size_t)(wv * 16 + lr) * S_LEN + k0s + kc * 32 + csw,
                        &VsT[kc][(wv * 16) * 32]);
    };

    ushort8 kreg[2], vreg[2];
    auto REGLOAD = [&](int kts) {
        const int k0s = kts * 64;
#pragma unroll
        for (int kf = 0; kf < 2; kf++)
            kreg[kf] = *(const ushort8*)&qkv[((size_t)(b * S_LEN + k0s + wv * 16 + lr) * 3 + 1) * D_MODEL
                                             + h * D_K + kf * 32 + csw];
#pragma unroll
        for (int kc = 0; kc < 2; kc++)
            vreg[kc] = *(const ushort8*)&VT[vtb + (size_t)(wv * 16 + lr) * S_LEN + k0s + kc * 32 + csw];
    };
    auto LDSW = [&]() {
#pragma unroll
        for (int kf = 0; kf < 2; kf++)
            *(ushort8*)&Ks[kf][(wv * 16) * 32 + lane * 8] = kreg[kf];
#pragma unroll
        for (int kc = 0; kc < 2; kc++)
            *(ushort8*)&VsT[kc][(wv * 16) * 32 + lane * 8] = vreg[kc];
    };

    short8 qfH[2];
#pragma unroll
    for (int kf = 0; kf < 2; kf++)
        qfH[kf] = *(const short8*)&qkv[((size_t)(b * S_LEN + qw0H + l15) * 3 + 0) * D_MODEL
                                       + h * D_K + kf * 32 + quad * 8];
    f32x4 accH[4] = {};
    float mqH = -INFINITY, lqH = 0.f;

    const int kbeg = role ? 17 : 0;
    const int kend = role ? qtH : 16;
    if (kbeg <= kend) {
        STAGE(kbeg);
        __syncthreads();
        for (int kt = kbeg; kt <= kend; kt++) {
            const bool more = kt < kend;
            if (more) REGLOAD(kt + 1);
            attn_step(&Ks[0][0], &VsT[0][0], Psw, qfH, accH, mqH, lqH,
                      kt * 64, qw0H, kt == qtH, l15, quad, qsw);
            __syncthreads();
            if (more) { LDSW(); __syncthreads(); }
        }
    }

    {
        const size_t unit = (size_t)(bh * 16 + (qtH - 16)) * 2 + role;
        float* Od = partO + unit * 4096 + (size_t)(wv * 16 + l15) * 64;
#pragma unroll
        for (int nj = 0; nj < 4; nj++)
            *(f32x4*)&Od[nj * 16 + quad * 4] = accH[nj];
        if (quad == 0) {
            float* ML = partML + unit * 128;
            ML[wv * 16 + l15]      = mqH;
            ML[64 + wv * 16 + l15] = lqH;
        }
    }

    if (!role) return;

    const int qw0L = qtL * 64 + wv * 16;
    short8 qfL[2];
#pragma unroll
    for (int kf = 0; kf < 2; kf++)
        qfL[kf] = *(const short8*)&qkv[((size_t)(b * S_LEN + qw0L + l15) * 3 + 0) * D_MODEL
                                       + h * D_K + kf * 32 + quad * 8];
    f32x4 accL[4] = {};
    float mqL = -INFINITY, lqL = 0.f;

    STAGE(0);
    __syncthreads();
    for (int kt = 0; kt <= qtL; kt++) {
        const bool more = kt < qtL;
        if (more) REGLOAD(kt + 1);
        attn_step(&Ks[0][0], &VsT[0][0], Psw, qfL, accL, mqL, lqL,
                  kt * 64, qw0L, kt == qtL, l15, quad, qsw);
        __syncthreads();
        if (more) { LDSW(); __syncthreads(); }
    }

    float invl = 1.f / lqL;
#pragma unroll
    for (int nj = 0; nj < 4; nj++) {
        ushort4 o;
        o.x = f2bf(accL[nj][0] * invl); o.y = f2bf(accL[nj][1] * invl);
        o.z = f2bf(accL[nj][2] * invl); o.w = f2bf(accL[nj][3] * invl);
        *(ushort4*)&out[(size_t)(b * S_LEN + qw0L + l15) * D_MODEL
                        + h * D_K + nj * 16 + quad * 4] = o;
    }
}

// ---------------------------------------------------------------------------
// Merge the two key-range partials of each H q-tile (log2 domain).
// ---------------------------------------------------------------------------
__global__ __launch_bounds__(256)
void attn_combine(const float* __restrict__ partO, const float* __restrict__ partML,
                  u16* __restrict__ out) {
    const int t16 = blockIdx.x & 15;
    const int bh  = blockIdx.x >> 4;
    const int h = bh & (N_HEADS - 1), b = bh >> 4;
    const int q0 = (t16 + 16) * 64;
    const int tid = threadIdx.x;
    const int q  = tid >> 2;
    const int d0 = (tid & 3) * 16;

    const size_t u0 = (size_t)(bh * 16 + t16) * 2;
    const float* O0 = partO + u0 * 4096;
    const float* O1 = O0 + 4096;
    const float* ML0 = partML + u0 * 128;
    const float* ML1 = ML0 + 128;

    float m0 = ML0[q], l0 = ML0[64 + q];
    float m1 = ML1[q], l1 = ML1[64 + q];
    float ms = fmaxf(m0, m1);
    float f0 = fast_exp2(m0 - ms), f1 = fast_exp2(m1 - ms);
    float inv = 1.f / (l0 * f0 + l1 * f1);
    f0 *= inv; f1 *= inv;
#pragma unroll
    for (int i = 0; i < 4; i++) {
        float4 a = *(const float4*)&O0[q * 64 + d0 + i * 4];
        float4 c = *(const float4*)&O1[q * 64 + d0 + i * 4];
        ushort4 o;
        o.x = f2bf(a.x * f0 + c.x * f1);
        o.y = f2bf(a.y * f0 + c.y * f1);
        o.z = f2bf(a.z * f0 + c.z * f1);
        o.w = f2bf(a.w * f0 + c.w * f1);
        *(ushort4*)&out[(size_t)(b * S_LEN + q0 + q) * D_MODEL + h * D_K + d0 + i * 4] = o;
    }
}

// ---------------------------------------------------------------------------
extern "C" void kernel_launch(void* const* d_in, const int* in_sizes, int n_in,
                              void* d_out, int out_size, void* d_ws, size_t ws_size,
                              hipStream_t stream) {
    const float* x    = (const float*)d_in[0];
    const int*   pos  = (const int*)d_in[1];
    const float* Wqkv = (const float*)d_in[2];
    const float* Wout = (const float*)d_in[3];
    float*       out  = (float*)d_out;

    const int M = B_SZ * S_LEN;   // 4096

    u16* qkvb = (u16*)d_ws;                            // 4096 x 3072
    u16* aob  = qkvb + (size_t)M * 3 * D_MODEL;        // 4096 x 1024
    u16* xb   = aob  + (size_t)M * D_MODEL;            // 4096 x 1024
    u16* wqb  = xb   + (size_t)M * D_MODEL;            // 3072 x 1024
    u16* wob  = wqb  + (size_t)3 * D_MODEL * D_MODEL;  // 1024 x 1024
    u16* vtb  = wob  + (size_t)D_MODEL * D_MODEL;      // 4096 x 1024
    float* partO  = (float*)(vtb + (size_t)M * D_MODEL);   // 1024 x 4096 f32
    float* partML = partO + (size_t)1024 * 4096;            // 1024 x 128 f32

    const int na4 = M * D_MODEL / 4;
    const int nb4 = 3 * D_MODEL * D_MODEL / 4;
    const int nc4 = D_MODEL * D_MODEL / 4;
    cast3_f32_bf16<<<(na4 + nb4 + nc4 + 255) / 256, 256, 0, stream>>>(
        x, xb, na4, Wqkv, wqb, nb4, Wout, wob, nc4);

    // gemm1 with fused RoPE + Q log2-scale epilogue (2-phase 128^2, verified)
    gemm_qkv_rope<<<dim3(3 * D_MODEL / 128, M / 128), 256, 0, stream>>>(
        xb, wqb, qkvb, pos, M, 3 * D_MODEL, D_MODEL);

    // V transpose only (RoPE fused into gemm1)
    vtrans<<<1024, 256, 0, stream>>>(qkvb, vtb);

    attn_mfma<<<1024, 256, 0, stream>>>(qkvb, vtb, aob, partO, partML);
    attn_combine<<<512, 256, 0, stream>>>(partO, partML, aob);

    gemm_bt_mfma_64r<<<dim3(D_MODEL / 128, M / 64), 256, 0, stream>>>(
        aob, wob, out, M, D_MODEL, D_MODEL);
}